// Round 1
// baseline (223.604 us; speedup 1.0000x reference)
//
#include <hip/hip_runtime.h>

#define EPSV 1e-5f

typedef short bf16x8 __attribute__((ext_vector_type(8)));
typedef float f32x4 __attribute__((ext_vector_type(4)));

static __device__ __forceinline__ unsigned short f2b(float f) {
  union { float f; unsigned u; } v; v.f = f;
  return (unsigned short)((v.u + 0x7fffu + ((v.u >> 16) & 1u)) >> 16);
}

// ---------- kernel 1: column stats of x (sum, sumsq per d) ----------
__global__ void k_stats1(const float* __restrict__ x, float* __restrict__ xsum,
                         float* __restrict__ xsq) {
  const int c = blockIdx.x * 256 + threadIdx.x;          // 0..1023
  const int r0 = blockIdx.y * 128;
  float s = 0.f, q = 0.f;
#pragma unroll 4
  for (int r = 0; r < 128; ++r) {
    float v = x[(size_t)(r0 + r) * 1024 + c];
    s += v;
    q = fmaf(v, v, q);
  }
  atomicAdd(&xsum[c], s);
  atomicAdd(&xsq[c], q);
}

// ---------- kernel 2: finalize BN1 -> packed params s1,t1 ----------
// pd layout per d (64 floats): [0:8)=s1, [8:16)=t1, [16:48)=W2*s2, [48:52)=t2c
__global__ void k_fin1(const float* __restrict__ W1, const float* __restrict__ g1,
                       const float* __restrict__ be1, const float* __restrict__ xsum,
                       const float* __restrict__ xsq, float* __restrict__ pd) {
  const int c = blockIdx.x * 256 + threadIdx.x;          // 0..8191
  const int d = c >> 3, i = c & 7;
  const float inv = 1.f / 8192.f;
  float mean = xsum[d] * inv;
  float var = xsq[d] * inv - mean * mean;
  float w = W1[c];
  float s1 = g1[c] * w * rsqrtf(w * w * var + EPSV);
  float t1 = be1[c] - s1 * mean;
  pd[d * 64 + i] = s1;
  pd[d * 64 + 8 + i] = t1;
}

// ---------- kernel 3: batch stats of dot (= h2pre - b2) per c2 ----------
__global__ __launch_bounds__(256) void k_stats2(const float* __restrict__ x,
    const float* __restrict__ pd, const float* __restrict__ W2,
    float* __restrict__ h2sum, float* __restrict__ h2sq) {
  __shared__ float red[8][32][8];
  const int t = threadIdx.x;
  const int dl = t & 31, slot = t >> 5;
  const int d = blockIdx.x * 32 + dl;
  const float4* pp = (const float4*)(pd + (size_t)d * 64);
  float s1v[8], t1v[8], w2v[32];
#pragma unroll
  for (int i = 0; i < 2; ++i) {
    float4 v = pp[i];
    s1v[i*4+0]=v.x; s1v[i*4+1]=v.y; s1v[i*4+2]=v.z; s1v[i*4+3]=v.w;
  }
#pragma unroll
  for (int i = 0; i < 2; ++i) {
    float4 v = pp[2+i];
    t1v[i*4+0]=v.x; t1v[i*4+1]=v.y; t1v[i*4+2]=v.z; t1v[i*4+3]=v.w;
  }
  const float4* wp = (const float4*)(W2 + (size_t)d * 32);
#pragma unroll
  for (int i = 0; i < 8; ++i) {
    float4 v = wp[i];
    w2v[i*4+0]=v.x; w2v[i*4+1]=v.y; w2v[i*4+2]=v.z; w2v[i*4+3]=v.w;
  }
  float s[4] = {0.f,0.f,0.f,0.f}, q[4] = {0.f,0.f,0.f,0.f};
  const int b0 = blockIdx.y * 256 + slot * 32;
  for (int r = 0; r < 32; ++r) {
    float xv = x[(size_t)(b0 + r) * 1024 + d];
    float a1[8];
#pragma unroll
    for (int i = 0; i < 8; ++i) a1[i] = fmaxf(fmaf(s1v[i], xv, t1v[i]), 0.f);
#pragma unroll
    for (int o = 0; o < 4; ++o) {
      float h = 0.f;
#pragma unroll
      for (int i = 0; i < 8; ++i) h = fmaf(a1[i], w2v[o*8+i], h);
      s[o] += h;
      q[o] = fmaf(h, h, q[o]);
    }
  }
#pragma unroll
  for (int j = 0; j < 4; ++j) {
    red[slot][dl][j] = s[j];
    red[slot][dl][4+j] = q[j];
  }
  __syncthreads();
  // 256 threads reduce 256 (d_local, stat) slots across the 8 b-slots
  const int d2l = t >> 3, j = t & 7;
  float v = 0.f;
#pragma unroll
  for (int p = 0; p < 8; ++p) v += red[p][d2l][j];
  const int c2 = (blockIdx.x * 32 + d2l) * 4 + (t & 3);
  if (j < 4) atomicAdd(&h2sum[c2], v);
  else       atomicAdd(&h2sq[c2], v);
}

// ---------- kernel 4: finalize BN2 -> W2s, t2c into pd ----------
__global__ void k_fin2(const float* __restrict__ W2, const float* __restrict__ g2,
                       const float* __restrict__ be2, const float* __restrict__ h2sum,
                       const float* __restrict__ h2sq, float* __restrict__ pd) {
  const int c2 = blockIdx.x * 256 + threadIdx.x;         // 0..4095
  const int d = c2 >> 2, o = c2 & 3;
  const float inv = 1.f / 8192.f;
  float m = h2sum[c2] * inv;
  float var = h2sq[c2] * inv - m * m;
  float s2 = g2[c2] * rsqrtf(var + EPSV);
  float t2 = be2[c2] - s2 * m;
  pd[d * 64 + 48 + o] = t2;
#pragma unroll
  for (int i = 0; i < 8; ++i)
    pd[d * 64 + 16 + o * 8 + i] = W2[(size_t)d * 32 + o * 8 + i] * s2;
}

// ---------- kernel 5: Wfc fp32 -> bf16 (layout kept: [j][c2]) ----------
__global__ void k_wfc(const float* __restrict__ wfc, unsigned short* __restrict__ wb) {
  const int i = (blockIdx.x * 256 + threadIdx.x) * 4;
  float4 v = *(const float4*)(wfc + i);
  ushort4 o;
  o.x = f2b(v.x); o.y = f2b(v.y); o.z = f2b(v.z); o.w = f2b(v.w);
  *(ushort4*)(wb + i) = o;
}

// ---------- kernel 6: fused A-gen + GEMM ----------
// BM=64, BN=256 (all N), BK=128 c2 (=32 d), K-split=2 (blockIdx.y)
// grid (128, 2) x 256 threads (4 waves); wave w owns n-range [w*64, w*64+64)
__global__ __launch_bounds__(256, 1) void k_gemm(const float* __restrict__ x,
    const float* __restrict__ pd, const unsigned short* __restrict__ wb,
    const float* __restrict__ bfc, float* __restrict__ out) {
  __shared__ __align__(16) unsigned short As[64 * 136];  // pad 128->136: 2-way only
  const int t = threadIdx.x;
  const int lane = t & 63;
  const int wv = t >> 6;
  const int m0 = blockIdx.x * 64;
  const int dks = blockIdx.y * 512;
  const int quad = lane >> 4;
  const int l15 = lane & 15;
  const int dl = t & 31, bs = t >> 5;

  f32x4 acc[4][4];
#pragma unroll
  for (int mt = 0; mt < 4; ++mt)
#pragma unroll
    for (int nt = 0; nt < 4; ++nt) {
      f32x4 z = {0.f, 0.f, 0.f, 0.f};
      acc[mt][nt] = z;
    }

  for (int ch = 0; ch < 16; ++ch) {
    const int d = dks + ch * 32 + dl;
    const float4* pp = (const float4*)(pd + (size_t)d * 64);
    float pv[52];
#pragma unroll
    for (int i = 0; i < 13; ++i) {
      float4 v = pp[i];
      pv[i*4+0]=v.x; pv[i*4+1]=v.y; pv[i*4+2]=v.z; pv[i*4+3]=v.w;
    }
    __syncthreads();   // previous MFMA phase done reading As
    // ---- A-gen: recompute a2 tile (64 b x 32 d x 4 o2) in bf16 ----
#pragma unroll
    for (int r = 0; r < 8; ++r) {
      const int bl = bs * 8 + r;
      float xv = x[(size_t)(m0 + bl) * 1024 + d];
      float a1[8];
#pragma unroll
      for (int i = 0; i < 8; ++i) a1[i] = fmaxf(fmaf(pv[i], xv, pv[8+i]), 0.f);
      unsigned short o4[4];
#pragma unroll
      for (int o = 0; o < 4; ++o) {
        float h = pv[48 + o];
#pragma unroll
        for (int i = 0; i < 8; ++i) h = fmaf(a1[i], pv[16 + o*8 + i], h);
        o4[o] = f2b(fmaxf(h, 0.f));
      }
      *(ushort4*)&As[bl * 136 + dl * 4] = make_ushort4(o4[0], o4[1], o4[2], o4[3]);
    }
    __syncthreads();
    // ---- MFMA phase ----
    const size_t kb = (size_t)(dks + ch * 32) * 4;       // global c2 base
#pragma unroll
    for (int kk = 0; kk < 4; ++kk) {
      bf16x8 af[4];
#pragma unroll
      for (int mt = 0; mt < 4; ++mt)
        af[mt] = *(const bf16x8*)&As[(mt*16 + l15) * 136 + kk*32 + quad*8];
#pragma unroll
      for (int nt = 0; nt < 4; ++nt) {
        const int n = wv * 64 + nt * 16 + l15;
        bf16x8 bfr = *(const bf16x8*)&wb[(size_t)n * 4096 + kb + kk*32 + quad*8];
#pragma unroll
        for (int mt = 0; mt < 4; ++mt)
          acc[mt][nt] = __builtin_amdgcn_mfma_f32_16x16x32_bf16(af[mt], bfr,
                                                                acc[mt][nt], 0, 0, 0);
      }
    }
  }
  // ---- epilogue: fp32 atomic merge of the 2 K-splits; split 0 adds bias ----
#pragma unroll
  for (int nt = 0; nt < 4; ++nt) {
    const int col = wv * 64 + nt * 16 + l15;
    const float bias = (blockIdx.y == 0) ? bfc[col] : 0.f;
#pragma unroll
    for (int mt = 0; mt < 4; ++mt) {
#pragma unroll
      for (int r = 0; r < 4; ++r) {
        const int row = m0 + mt * 16 + quad * 4 + r;
        atomicAdd(&out[(size_t)row * 256 + col], acc[mt][nt][r] + bias);
      }
    }
  }
}

extern "C" void kernel_launch(void* const* d_in, const int* in_sizes, int n_in,
                              void* d_out, int out_size, void* d_ws, size_t ws_size,
                              hipStream_t stream) {
  const float* x   = (const float*)d_in[0];
  const float* W1  = (const float*)d_in[1];
  // d_in[2] = b1 (cancels in BN1), d_in[6] = b2 (cancels in BN2)
  const float* g1  = (const float*)d_in[3];
  const float* be1 = (const float*)d_in[4];
  const float* W2  = (const float*)d_in[5];
  const float* g2  = (const float*)d_in[7];
  const float* be2 = (const float*)d_in[8];
  const float* Wfc = (const float*)d_in[9];
  const float* bfc = (const float*)d_in[10];
  float* out = (float*)d_out;

  char* ws = (char*)d_ws;
  unsigned short* wb = (unsigned short*)ws;                 // 2 MB  bf16 Wfc
  float* pd    = (float*)(ws + (2u << 20));                 // 256 KB packed params
  float* stats = (float*)(ws + (2u << 20) + (256u << 10));  // 40 KB accumulators
  float* xsum   = stats;
  float* xsq    = stats + 1024;
  float* h2sum  = stats + 2048;
  float* h2sq   = stats + 2048 + 4096;

  hipMemsetAsync(stats, 0, (size_t)(1024*2 + 4096*2) * sizeof(float), stream);
  hipMemsetAsync(d_out, 0, (size_t)out_size * sizeof(float), stream);

  k_wfc   <<<dim3(1024),     256, 0, stream>>>(Wfc, wb);
  k_stats1<<<dim3(4, 64),    256, 0, stream>>>(x, xsum, xsq);
  k_fin1  <<<dim3(32),       256, 0, stream>>>(W1, g1, be1, xsum, xsq, pd);
  k_stats2<<<dim3(32, 32),   256, 0, stream>>>(x, pd, W2, h2sum, h2sq);
  k_fin2  <<<dim3(16),       256, 0, stream>>>(W2, g2, be2, h2sum, h2sq, pd);
  k_gemm  <<<dim3(128, 2),   256, 0, stream>>>(x, pd, wb, bfc, out);
}